// Round 11
// baseline (6141.610 us; speedup 1.0000x reference)
//
#include <hip/hip_runtime.h>

// ---------------------------------------------------------------------------
// MHLP predictor — clean baseline (first full-pass candidate).
// Root cause of R0-R9 (10 rounds of exact-zero outputs): float inputs are
// FLOAT32 and output is FLOAT32 — the test's "bf16" label is template text.
// Reading f32 weights as bf16 made LN variances inf -> rstd=0 -> all-zero
// outputs, bit-identical to an unwritten buffer. R10 proved the f32 scalar
// kernel correct (absmax 2.4e-4 < 3.79e-3) and proved one shared runtime
// (my eager sync/memcpy poisoned graph capture). This round: kernel_launch
// contains EXACTLY one kernel launch on the passed stream. Capture-legal.
// Optimization starts next round with dur_us + rocprof in hand.
// ---------------------------------------------------------------------------

__device__ __forceinline__ float dot64(const float* __restrict__ w,
                                       const float* __restrict__ x) {
  float acc = 0.f;
#pragma unroll 8
  for (int j = 0; j < 64; ++j) acc += w[j] * x[j];
  return acc;
}
__device__ __forceinline__ float dot128(const float* __restrict__ w,
                                        const float* __restrict__ x) {
  float acc = 0.f;
#pragma unroll 8
  for (int j = 0; j < 128; ++j) acc += w[j] * x[j];
  return acc;
}

__global__ void mhlp_scalar(
    const int* __restrict__ g_hw, const int* __restrict__ g_op, const int* __restrict__ g_wd,
    const float* __restrict__ g_hwe,
    const float* __restrict__ g_W1,  const float* __restrict__ g_b1,
    const float* __restrict__ g_W2,  const float* __restrict__ g_b2,
    const float* __restrict__ g_ln1g, const float* __restrict__ g_ln1b,
    const float* __restrict__ g_ipw, const float* __restrict__ g_ipb,
    const float* __restrict__ g_opw, const float* __restrict__ g_opb,
    const float* __restrict__ g_ln2g, const float* __restrict__ g_ln2b,
    const float* __restrict__ g_W3,  const float* __restrict__ g_b3,
    const float* __restrict__ g_W4,  const float* __restrict__ g_b4,
    float* __restrict__ g_out)
{
  const int i = blockIdx.x * blockDim.x + threadIdx.x;  // exactly B threads

  int cell[5];
#pragma unroll
  for (int l = 0; l < 5; ++l)
    cell[l] = 15 * l + g_op[i * 5 + l] * 3 + g_wd[i * 5 + l];

  // h = relu(onehot @ W1^T + b1)  [128]
  float h[128];
  for (int n = 0; n < 128; ++n) {
    float s = g_b1[n];
    const float* row = g_W1 + n * 75;
#pragma unroll
    for (int l = 0; l < 5; ++l) s += row[cell[l]];
    h[n] = s > 0.f ? s : 0.f;
  }

  // arch = LN1(h @ W2^T + b2)  [64]
  float ar[64];
  {
    float mean = 0.f;
    for (int n = 0; n < 64; ++n) {
      const float s = g_b2[n] + dot128(g_W2 + n * 128, h);
      ar[n] = s; mean += s;
    }
    mean *= (1.f / 64.f);
    float var = 0.f;
    for (int n = 0; n < 64; ++n) { const float d = ar[n] - mean; var += d * d; }
    var *= (1.f / 64.f);
    const float rstd = rsqrtf(var + 1e-5f);
    for (int n = 0; n < 64; ++n)
      ar[n] = (ar[n] - mean) * rstd * g_ln1g[n] + g_ln1b[n];
  }

  // token 0 = hw_embed[hw]
  const int hw = g_hw[i];
  float x0[64];
  for (int n = 0; n < 64; ++n) x0[n] = g_hwe[hw * 64 + n];

  // qkv streaming: per-head scores + stash v
  float v0[64], v1[64];
  float s00[4] = {0.f, 0.f, 0.f, 0.f}, s01[4] = {0.f, 0.f, 0.f, 0.f};
  float s10[4] = {0.f, 0.f, 0.f, 0.f}, s11[4] = {0.f, 0.f, 0.f, 0.f};
  for (int n = 0; n < 64; ++n) {
    const float qb = g_ipb[n];
    const float kb = g_ipb[64 + n];
    const float vb = g_ipb[128 + n];
    const float q0 = qb + dot64(g_ipw + n * 64, x0);
    const float q1 = qb + dot64(g_ipw + n * 64, ar);
    const float k0 = kb + dot64(g_ipw + (64 + n) * 64, x0);
    const float k1 = kb + dot64(g_ipw + (64 + n) * 64, ar);
    v0[n] = vb + dot64(g_ipw + (128 + n) * 64, x0);
    v1[n] = vb + dot64(g_ipw + (128 + n) * 64, ar);
    const int hh = n >> 4;
    s00[hh] += q0 * k0; s01[hh] += q0 * k1;
    s10[hh] += q1 * k0; s11[hh] += q1 * k1;
  }

  // softmax per head (scale 1/sqrt(16) = 0.25)
  float a00[4], a01[4], a10[4], a11[4];
#pragma unroll
  for (int hh = 0; hh < 4; ++hh) {
    const float t00 = s00[hh] * 0.25f, t01 = s01[hh] * 0.25f;
    const float t10 = s10[hh] * 0.25f, t11 = s11[hh] * 0.25f;
    const float mA = fmaxf(t00, t01);
    const float e0 = __expf(t00 - mA), e1 = __expf(t01 - mA);
    const float iA = 1.f / (e0 + e1);
    a00[hh] = e0 * iA; a01[hh] = e1 * iA;
    const float mB = fmaxf(t10, t11);
    const float f0 = __expf(t10 - mB), f1 = __expf(t11 - mB);
    const float iB = 1.f / (f0 + f1);
    a10[hh] = f0 * iB; a11[hh] = f1 * iB;
  }

  float c0[64], c1[64];
  for (int n = 0; n < 64; ++n) {
    const int hh = n >> 4;
    c0[n] = a00[hh] * v0[n] + a01[hh] * v1[n];
    c1[n] = a10[hh] * v0[n] + a11[hh] * v1[n];
  }

  // out_proj + residual + LN2 per token, mean-pool
  float pooled[64];
  {
    float t[64];
    float mean = 0.f;
    for (int n = 0; n < 64; ++n) {
      const float s = g_opb[n] + dot64(g_opw + n * 64, c0) + x0[n];
      t[n] = s; mean += s;
    }
    mean *= (1.f / 64.f);
    float var = 0.f;
    for (int n = 0; n < 64; ++n) { const float d = t[n] - mean; var += d * d; }
    var *= (1.f / 64.f);
    const float rstd = rsqrtf(var + 1e-5f);
    for (int n = 0; n < 64; ++n)
      pooled[n] = 0.5f * ((t[n] - mean) * rstd * g_ln2g[n] + g_ln2b[n]);

    mean = 0.f;
    for (int n = 0; n < 64; ++n) {
      const float s = g_opb[n] + dot64(g_opw + n * 64, c1) + ar[n];
      t[n] = s; mean += s;
    }
    mean *= (1.f / 64.f);
    var = 0.f;
    for (int n = 0; n < 64; ++n) { const float d = t[n] - mean; var += d * d; }
    var *= (1.f / 64.f);
    const float rstd2 = rsqrtf(var + 1e-5f);
    for (int n = 0; n < 64; ++n)
      pooled[n] += 0.5f * ((t[n] - mean) * rstd2 * g_ln2g[n] + g_ln2b[n]);
  }

  // head: relu(pooled @ W3^T + b3) . W4 + b4
  float acc = g_b4[0];
  for (int m = 0; m < 32; ++m) {
    float y = g_b3[m] + dot64(g_W3 + m * 64, pooled);
    y = y > 0.f ? y : 0.f;
    acc += y * g_W4[m];
  }

  g_out[i] = acc;
}

extern "C" void kernel_launch(void* const* d_in, const int* in_sizes, int n_in,
                              void* d_out, int out_size, void* d_ws, size_t ws_size,
                              hipStream_t stream) {
  (void)in_sizes; (void)n_in; (void)d_ws; (void)ws_size; (void)out_size;
  mhlp_scalar<<<1024, 256, 0, stream>>>(
      (const int*)d_in[0], (const int*)d_in[1], (const int*)d_in[2],
      (const float*)d_in[3],
      (const float*)d_in[4],  (const float*)d_in[5],
      (const float*)d_in[6],  (const float*)d_in[7],
      (const float*)d_in[8],  (const float*)d_in[9],
      (const float*)d_in[10], (const float*)d_in[11],
      (const float*)d_in[12], (const float*)d_in[13],
      (const float*)d_in[14], (const float*)d_in[15],
      (const float*)d_in[16], (const float*)d_in[17],
      (const float*)d_in[18], (const float*)d_in[19],
      (float*)d_out);
}

// Round 12
// 1483.027 us; speedup vs baseline: 4.1413x; 4.1413x over previous
//
#include <hip/hip_runtime.h>

// ---------------------------------------------------------------------------
// MHLP predictor — no-spill register-resident version.
// R11 baseline (6141 us) was 100% scratch-spill-bound: 23.7 GB HBM/dispatch,
// VALUBusy 5%. Fix: lane=sample with ALL loops fully unrolled (static
// indexing -> arrays in VGPRs), token-0 path precomputed per hw_idx (only 4
// rows) into d_ws tables (q0/k0/s00/u0), out_proj folded linearly, and a
// 2-kernel split (encoder -> arT[64][B] in d_ws -> attention+head) with
// __launch_bounds__(256,2) to cap VGPRs at 256 (2 waves/SIMD).
// Per-sample MACs 44K -> 26.5K; predicted ~150-280 us, VALU-bound.
// ---------------------------------------------------------------------------

#define BTOT 262144

// d_ws float layout:
//   [0..256)     q0t[4][64]
//   [256..512)   k0t[4][64]
//   [512..768)   u0t[4][64]   (= out_proj_w . v0(hw))
//   [768..784)   s00t[4][4]   (raw q0.k0 per head, unscaled)
//   [4096..)     arT[64][BTOT] (transposed LN1 output)

// ---------------- precompute: token-0 tables (4 hw rows) -------------------
__global__ void k_pre(const float* __restrict__ hwe,
                      const float* __restrict__ ipw, const float* __restrict__ ipb,
                      const float* __restrict__ opw,
                      float* __restrict__ ws) {
  __shared__ float sq[256], sk[256], sv[256];
  const int t = threadIdx.x;          // 256 threads: r = t>>6 (hw row), n = t&63
  const int r = t >> 6, n = t & 63;
  const float* x = hwe + r * 64;
  float q = ipb[n], k = ipb[64 + n], v = ipb[128 + n];
#pragma unroll
  for (int j = 0; j < 64; ++j) {
    q += ipw[n * 64 + j] * x[j];
    k += ipw[(64 + n) * 64 + j] * x[j];
    v += ipw[(128 + n) * 64 + j] * x[j];
  }
  sq[t] = q; sk[t] = k; sv[t] = v;
  ws[t] = q; ws[256 + t] = k;
  __syncthreads();
  float u = 0.f;
#pragma unroll
  for (int j = 0; j < 64; ++j) u += opw[n * 64 + j] * sv[r * 64 + j];
  ws[512 + t] = u;
  if (t < 16) {
    const int rr = t >> 2, h = t & 3;
    float s = 0.f;
#pragma unroll
    for (int d = 0; d < 16; ++d)
      s += sq[rr * 64 + h * 16 + d] * sk[rr * 64 + h * 16 + d];
    ws[768 + t] = s;
  }
}

// ---------------- K1: encoder -> arT[64][B] --------------------------------
__global__ __launch_bounds__(256, 2) void k_enc(
    const int* __restrict__ g_op, const int* __restrict__ g_wd,
    const float* __restrict__ g_W1,  const float* __restrict__ g_b1,
    const float* __restrict__ g_W2,  const float* __restrict__ g_b2,
    const float* __restrict__ g_ln1g, const float* __restrict__ g_ln1b,
    float* __restrict__ arT) {
  const int i = blockIdx.x * 256 + threadIdx.x;

  int c0 = g_op[i * 5 + 0] * 3 + g_wd[i * 5 + 0];
  int c1 = 15 + g_op[i * 5 + 1] * 3 + g_wd[i * 5 + 1];
  int c2 = 30 + g_op[i * 5 + 2] * 3 + g_wd[i * 5 + 2];
  int c3 = 45 + g_op[i * 5 + 3] * 3 + g_wd[i * 5 + 3];
  int c4 = 60 + g_op[i * 5 + 4] * 3 + g_wd[i * 5 + 4];

  // h = relu(b1 + 5 gathered W1 columns)   [128 VGPRs]
  float h[128];
#pragma unroll
  for (int n = 0; n < 128; ++n) {
    const float* row = g_W1 + n * 75;
    float s = g_b1[n] + row[c0] + row[c1] + row[c2] + row[c3] + row[c4];
    h[n] = s > 0.f ? s : 0.f;
  }

  // ar_raw = W2 . h + b2 ; LN1 (lane-local)
  float ar[64];
#pragma unroll
  for (int n = 0; n < 64; ++n) {
    const float* w = g_W2 + n * 128;
    float a = g_b2[n];
#pragma unroll
    for (int j = 0; j < 128; ++j) a += w[j] * h[j];
    ar[n] = a;
  }
  float mean = 0.f;
#pragma unroll
  for (int n = 0; n < 64; ++n) mean += ar[n];
  mean *= (1.f / 64.f);
  float var = 0.f;
#pragma unroll
  for (int n = 0; n < 64; ++n) { const float d = ar[n] - mean; var += d * d; }
  var *= (1.f / 64.f);
  const float rstd = rsqrtf(var + 1e-5f);
#pragma unroll
  for (int n = 0; n < 64; ++n) {
    const float v = (ar[n] - mean) * rstd * g_ln1g[n] + g_ln1b[n];
    arT[n * BTOT + i] = v;   // transposed, coalesced
  }
}

// ---------------- K2: attention + head -> out ------------------------------
__global__ __launch_bounds__(256, 2) void k_attn(
    const int* __restrict__ g_hw,
    const float* __restrict__ g_hwe,
    const float* __restrict__ g_ipw, const float* __restrict__ g_ipb,
    const float* __restrict__ g_opw, const float* __restrict__ g_opb,
    const float* __restrict__ g_ln2g, const float* __restrict__ g_ln2b,
    const float* __restrict__ g_W3,  const float* __restrict__ g_b3,
    const float* __restrict__ g_W4,  const float* __restrict__ g_b4,
    const float* __restrict__ ws,
    float* __restrict__ g_out) {
  const int i = blockIdx.x * 256 + threadIdx.x;
  const int hw = g_hw[i];

  const float* arT = ws + 4096;
  float ar[64];
#pragma unroll
  for (int n = 0; n < 64; ++n) ar[n] = arT[n * BTOT + i];   // coalesced

  const float* q0r = ws + hw * 64;          // token-0 q (table)
  const float* k0r = ws + 256 + hw * 64;    // token-0 k
  const float* u0r = ws + 512 + hw * 64;    // opw . v0
  const float* x0r = g_hwe + hw * 64;       // token-0 residual

  // token-1 qkv + scores; v1 kept in regs
  float v1[64];
  float s01[4] = {0.f, 0.f, 0.f, 0.f};
  float s10[4] = {0.f, 0.f, 0.f, 0.f};
  float s11[4] = {0.f, 0.f, 0.f, 0.f};
#pragma unroll
  for (int n = 0; n < 64; ++n) {
    const float* wq = g_ipw + n * 64;
    const float* wk = g_ipw + (64 + n) * 64;
    const float* wv = g_ipw + (128 + n) * 64;
    float q1 = g_ipb[n], k1 = g_ipb[64 + n], vv = g_ipb[128 + n];
#pragma unroll
    for (int j = 0; j < 64; ++j) {
      q1 += wq[j] * ar[j];
      k1 += wk[j] * ar[j];
      vv += wv[j] * ar[j];
    }
    v1[n] = vv;
    const float q0n = q0r[n], k0n = k0r[n];
    s01[n >> 4] += q0n * k1;
    s10[n >> 4] += q1 * k0n;
    s11[n >> 4] += q1 * k1;
  }

  // softmax per head (scale 1/4); s00 from table
  float a00[4], a01[4], a10[4], a11[4];
#pragma unroll
  for (int h = 0; h < 4; ++h) {
    const float t00 = ws[768 + hw * 4 + h] * 0.25f;
    const float t01 = s01[h] * 0.25f;
    const float t10 = s10[h] * 0.25f;
    const float t11 = s11[h] * 0.25f;
    const float mA = fmaxf(t00, t01);
    const float e0 = __expf(t00 - mA), e1 = __expf(t01 - mA);
    const float iA = 1.f / (e0 + e1);
    a00[h] = e0 * iA; a01[h] = e1 * iA;
    const float mB = fmaxf(t10, t11);
    const float f0 = __expf(t10 - mB), f1 = __expf(t11 - mB);
    const float iB = 1.f / (f0 + f1);
    a10[h] = f0 * iB; a11[h] = f1 * iB;
  }

  // u1 = opw . v1
  float u1[64];
#pragma unroll
  for (int m = 0; m < 64; ++m) {
    const float* w = g_opw + m * 64;
    float a = 0.f;
#pragma unroll
    for (int j = 0; j < 64; ++j) a += w[j] * v1[j];
    u1[m] = a;
  }

  // token0: t0 = opb + a00*u0 + a01*u1 + x0 ; LN2 ; pooled = 0.5*ln
  float pooled[64];
  {
    float t0[64];
    float mean = 0.f;
#pragma unroll
    for (int n = 0; n < 64; ++n) {
      const int h = n >> 4;
      const float s = g_opb[n] + a00[h] * u0r[n] + a01[h] * u1[n] + x0r[n];
      t0[n] = s; mean += s;
    }
    mean *= (1.f / 64.f);
    float var = 0.f;
#pragma unroll
    for (int n = 0; n < 64; ++n) { const float d = t0[n] - mean; var += d * d; }
    var *= (1.f / 64.f);
    const float rstd = rsqrtf(var + 1e-5f);
#pragma unroll
    for (int n = 0; n < 64; ++n)
      pooled[n] = 0.5f * ((t0[n] - mean) * rstd * g_ln2g[n] + g_ln2b[n]);
  }
  // token1: t1 = opb + a10*u0 + a11*u1 + ar ; LN2 ; pooled += 0.5*ln
  {
    float t1[64];
    float mean = 0.f;
#pragma unroll
    for (int n = 0; n < 64; ++n) {
      const int h = n >> 4;
      const float s = g_opb[n] + a10[h] * u0r[n] + a11[h] * u1[n] + ar[n];
      t1[n] = s; mean += s;
    }
    mean *= (1.f / 64.f);
    float var = 0.f;
#pragma unroll
    for (int n = 0; n < 64; ++n) { const float d = t1[n] - mean; var += d * d; }
    var *= (1.f / 64.f);
    const float rstd = rsqrtf(var + 1e-5f);
#pragma unroll
    for (int n = 0; n < 64; ++n)
      pooled[n] += 0.5f * ((t1[n] - mean) * rstd * g_ln2g[n] + g_ln2b[n]);
  }

  // head
  float acc = g_b4[0];
#pragma unroll
  for (int m = 0; m < 32; ++m) {
    const float* w = g_W3 + m * 64;
    float y = g_b3[m];
#pragma unroll
    for (int j = 0; j < 64; ++j) y += w[j] * pooled[j];
    y = y > 0.f ? y : 0.f;
    acc += y * g_W4[m];
  }
  g_out[i] = acc;
}

extern "C" void kernel_launch(void* const* d_in, const int* in_sizes, int n_in,
                              void* d_out, int out_size, void* d_ws, size_t ws_size,
                              hipStream_t stream) {
  (void)in_sizes; (void)n_in; (void)out_size; (void)ws_size;
  float* ws = (float*)d_ws;

  k_pre<<<1, 256, 0, stream>>>(
      (const float*)d_in[3], (const float*)d_in[10], (const float*)d_in[11],
      (const float*)d_in[12], ws);

  k_enc<<<BTOT / 256, 256, 0, stream>>>(
      (const int*)d_in[1], (const int*)d_in[2],
      (const float*)d_in[4], (const float*)d_in[5],
      (const float*)d_in[6], (const float*)d_in[7],
      (const float*)d_in[8], (const float*)d_in[9],
      ws + 4096);

  k_attn<<<BTOT / 256, 256, 0, stream>>>(
      (const int*)d_in[0],
      (const float*)d_in[3],
      (const float*)d_in[10], (const float*)d_in[11],
      (const float*)d_in[12], (const float*)d_in[13],
      (const float*)d_in[14], (const float*)d_in[15],
      (const float*)d_in[16], (const float*)d_in[17],
      (const float*)d_in[18], (const float*)d_in[19],
      ws, (float*)d_out);
}

// Round 13
// 658.228 us; speedup vs baseline: 9.3305x; 2.2531x over previous
//
#include <hip/hip_runtime.h>

// ---------------------------------------------------------------------------
// MHLP predictor — I$-friendly rolled-loop version.
// R12 (1483 us) was instruction-fetch-bound: fully-unrolled bodies (~200 KB
// code) thrashed the 32 KB I$ (VALUBusy 18%, HBM 3%, no spill). This round
// keeps arrays register-resident but rolls the hot loops as outer products so
// rolled loop vars never index a register array:
//   k_enc : roll j(128): h_j on the fly, ar[n] += W2T[j][n]*h_j (n unrolled)
//   k_attn: roll n per head: q1/k1/v_n, u1[m] += opwT[n][m]*v_n (m unrolled)
// W2T/opwT precomputed in k_pre (d_ws). arT stored float4-interleaved
// [16][B][4] for vectorized coalesced round-trip.
// Predict ~200-350 us, VALUBusy 50-80%, absmax unchanged ~2.4e-3.
// ---------------------------------------------------------------------------

#define BTOT 262144

// d_ws float layout:
//   [0..256)        q0t[4][64]
//   [256..512)      k0t[4][64]
//   [512..768)      u0t[4][64]    (= out_proj_w . v0(hw))
//   [768..784)      s00t[4][4]    (raw q0.k0 per head, unscaled)
//   [1024..5120)    opwT[64][64]  (opwT[n][m] = opw[m][n])
//   [8192..16384)   W2T[128][64]  (W2T[j][n]  = W2[n][j])
//   [16384..)       arT4: float4 [16][BTOT]  (LN1 output, interleaved)
#define WS_OPWT 1024
#define WS_W2T  8192
#define WS_ART  16384

// ---------------- precompute: tables + transposes --------------------------
__global__ void k_pre(const float* __restrict__ hwe,
                      const float* __restrict__ ipw, const float* __restrict__ ipb,
                      const float* __restrict__ opw, const float* __restrict__ W2,
                      float* __restrict__ ws) {
  __shared__ float sq[256], sk[256], sv[256];
  const int t = threadIdx.x;          // 256 threads: r = t>>6 (hw row), n = t&63
  const int r = t >> 6, n = t & 63;
  const float* x = hwe + r * 64;
  float q = ipb[n], k = ipb[64 + n], v = ipb[128 + n];
#pragma unroll
  for (int j = 0; j < 64; ++j) {
    q += ipw[n * 64 + j] * x[j];
    k += ipw[(64 + n) * 64 + j] * x[j];
    v += ipw[(128 + n) * 64 + j] * x[j];
  }
  sq[t] = q; sk[t] = k; sv[t] = v;
  ws[t] = q; ws[256 + t] = k;
  __syncthreads();
  float u = 0.f;
#pragma unroll
  for (int j = 0; j < 64; ++j) u += opw[n * 64 + j] * sv[r * 64 + j];
  ws[512 + t] = u;
  if (t < 16) {
    const int rr = t >> 2, h = t & 3;
    float s = 0.f;
#pragma unroll
    for (int d = 0; d < 16; ++d)
      s += sq[rr * 64 + h * 16 + d] * sk[rr * 64 + h * 16 + d];
    ws[768 + t] = s;
  }
  // opwT[n][m] = opw[m][n]
  for (int i = t; i < 4096; i += 256) {
    const int nn = i >> 6, m = i & 63;
    ws[WS_OPWT + i] = opw[m * 64 + nn];
  }
  // W2T[j][n] = W2[n][j]
  for (int i = t; i < 8192; i += 256) {
    const int j = i >> 6, nn = i & 63;
    ws[WS_W2T + i] = W2[nn * 128 + j];
  }
}

// ---------------- K1: encoder -> arT4 --------------------------------------
__global__ __launch_bounds__(256) void k_enc(
    const int* __restrict__ g_op, const int* __restrict__ g_wd,
    const float* __restrict__ g_W1,  const float* __restrict__ g_b1,
    const float* __restrict__ g_b2,
    const float* __restrict__ g_ln1g, const float* __restrict__ g_ln1b,
    const float* __restrict__ ws) {
  const int i = blockIdx.x * 256 + threadIdx.x;

  const int c0 = g_op[i * 5 + 0] * 3 + g_wd[i * 5 + 0];
  const int c1 = 15 + g_op[i * 5 + 1] * 3 + g_wd[i * 5 + 1];
  const int c2 = 30 + g_op[i * 5 + 2] * 3 + g_wd[i * 5 + 2];
  const int c3 = 45 + g_op[i * 5 + 3] * 3 + g_wd[i * 5 + 3];
  const int c4 = 60 + g_op[i * 5 + 4] * 3 + g_wd[i * 5 + 4];

  float ar[64];
#pragma unroll
  for (int n = 0; n < 64; ++n) ar[n] = g_b2[n];

  const float* w2t = ws + WS_W2T;
#pragma unroll 2
  for (int j = 0; j < 128; ++j) {
    const float* row = g_W1 + j * 75;
    float hj = g_b1[j] + row[c0] + row[c1] + row[c2] + row[c3] + row[c4];
    hj = hj > 0.f ? hj : 0.f;
    const float* w = w2t + j * 64;
#pragma unroll
    for (int n = 0; n < 64; ++n) ar[n] += w[n] * hj;
  }

  float mean = 0.f;
#pragma unroll
  for (int n = 0; n < 64; ++n) mean += ar[n];
  mean *= (1.f / 64.f);
  float var = 0.f;
#pragma unroll
  for (int n = 0; n < 64; ++n) { const float d = ar[n] - mean; var += d * d; }
  var *= (1.f / 64.f);
  const float rstd = rsqrtf(var + 1e-5f);
#pragma unroll
  for (int n = 0; n < 64; ++n)
    ar[n] = (ar[n] - mean) * rstd * g_ln1g[n] + g_ln1b[n];

  float4* arT4 = (float4*)(ws + WS_ART);
#pragma unroll
  for (int k = 0; k < 16; ++k) {
    float4 v;
    v.x = ar[4 * k]; v.y = ar[4 * k + 1]; v.z = ar[4 * k + 2]; v.w = ar[4 * k + 3];
    arT4[(size_t)k * BTOT + i] = v;
  }
}

// ---------------- K2: attention + head -> out ------------------------------
__global__ __launch_bounds__(256) void k_attn(
    const int* __restrict__ g_hw,
    const float* __restrict__ g_hwe,
    const float* __restrict__ g_ipw, const float* __restrict__ g_ipb,
    const float* __restrict__ g_opb,
    const float* __restrict__ g_ln2g, const float* __restrict__ g_ln2b,
    const float* __restrict__ g_W3,  const float* __restrict__ g_b3,
    const float* __restrict__ g_W4,  const float* __restrict__ g_b4,
    const float* __restrict__ ws,
    float* __restrict__ g_out) {
  const int i = blockIdx.x * 256 + threadIdx.x;
  const int hw = g_hw[i];

  float ar[64];
  const float4* arT4 = (const float4*)(ws + WS_ART);
#pragma unroll
  for (int k = 0; k < 16; ++k) {
    const float4 v = arT4[(size_t)k * BTOT + i];
    ar[4 * k] = v.x; ar[4 * k + 1] = v.y; ar[4 * k + 2] = v.z; ar[4 * k + 3] = v.w;
  }

  const float* q0r = ws + hw * 64;
  const float* k0r = ws + 256 + hw * 64;
  const float* u0r = ws + 512 + hw * 64;
  const float* opwT = ws + WS_OPWT;

  float u1[64];
#pragma unroll
  for (int m = 0; m < 64; ++m) u1[m] = 0.f;

  float s01[4], s10[4], s11[4];
#pragma unroll
  for (int h = 0; h < 4; ++h) {
    float a01 = 0.f, a10 = 0.f, a11 = 0.f;
#pragma unroll 1
    for (int nn = 0; nn < 16; ++nn) {
      const int n = h * 16 + nn;
      const float* wq = g_ipw + n * 64;
      const float* wk = g_ipw + (64 + n) * 64;
      const float* wv = g_ipw + (128 + n) * 64;
      float q1 = g_ipb[n], k1 = g_ipb[64 + n], vv = g_ipb[128 + n];
#pragma unroll
      for (int j = 0; j < 64; ++j) {
        q1 += wq[j] * ar[j];
        k1 += wk[j] * ar[j];
        vv += wv[j] * ar[j];
      }
      const float q0n = q0r[n], k0n = k0r[n];
      a01 += q0n * k1;
      a10 += q1 * k0n;
      a11 += q1 * k1;
      const float* ot = opwT + n * 64;
#pragma unroll
      for (int m = 0; m < 64; ++m) u1[m] += ot[m] * vv;
    }
    s01[h] = a01; s10[h] = a10; s11[h] = a11;
  }

  // softmax per head (scale 1/sqrt(16) = 0.25); s00 from table
  float a00[4], a01c[4], a10c[4], a11c[4];
#pragma unroll
  for (int h = 0; h < 4; ++h) {
    const float t00 = ws[768 + hw * 4 + h] * 0.25f;
    const float t01 = s01[h] * 0.25f;
    const float t10 = s10[h] * 0.25f;
    const float t11 = s11[h] * 0.25f;
    const float mA = fmaxf(t00, t01);
    const float e0 = __expf(t00 - mA), e1 = __expf(t01 - mA);
    const float iA = 1.f / (e0 + e1);
    a00[h] = e0 * iA; a01c[h] = e1 * iA;
    const float mB = fmaxf(t10, t11);
    const float f0 = __expf(t10 - mB), f1 = __expf(t11 - mB);
    const float iB = 1.f / (f0 + f1);
    a10c[h] = f0 * iB; a11c[h] = f1 * iB;
  }

  float pooled[64];
  // token1 first (frees ar): t1 = opb + a10*u0 + a11*u1 + ar ; LN2
  {
    float t1[64];
    float mean = 0.f;
#pragma unroll
    for (int n = 0; n < 64; ++n) {
      const int h = n >> 4;
      const float s = g_opb[n] + a10c[h] * u0r[n] + a11c[h] * u1[n] + ar[n];
      t1[n] = s; mean += s;
    }
    mean *= (1.f / 64.f);
    float var = 0.f;
#pragma unroll
    for (int n = 0; n < 64; ++n) { const float d = t1[n] - mean; var += d * d; }
    var *= (1.f / 64.f);
    const float rstd = rsqrtf(var + 1e-5f);
#pragma unroll
    for (int n = 0; n < 64; ++n)
      pooled[n] = 0.5f * ((t1[n] - mean) * rstd * g_ln2g[n] + g_ln2b[n]);
  }
  // token0: t0 = opb + a00*u0 + a01*u1 + x0 ; LN2
  {
    const float* x0r = g_hwe + hw * 64;
    float t0[64];
    float mean = 0.f;
#pragma unroll
    for (int n = 0; n < 64; ++n) {
      const int h = n >> 4;
      const float s = g_opb[n] + a00[h] * u0r[n] + a01c[h] * u1[n] + x0r[n];
      t0[n] = s; mean += s;
    }
    mean *= (1.f / 64.f);
    float var = 0.f;
#pragma unroll
    for (int n = 0; n < 64; ++n) { const float d = t0[n] - mean; var += d * d; }
    var *= (1.f / 64.f);
    const float rstd = rsqrtf(var + 1e-5f);
#pragma unroll
    for (int n = 0; n < 64; ++n)
      pooled[n] += 0.5f * ((t0[n] - mean) * rstd * g_ln2g[n] + g_ln2b[n]);
  }

  // head: rolled over m, inner unrolled
  float acc = g_b4[0];
#pragma unroll 1
  for (int m = 0; m < 32; ++m) {
    const float* w = g_W3 + m * 64;
    float y = g_b3[m];
#pragma unroll
    for (int j = 0; j < 64; ++j) y += w[j] * pooled[j];
    y = y > 0.f ? y : 0.f;
    acc += y * g_W4[m];
  }
  g_out[i] = acc;
}

extern "C" void kernel_launch(void* const* d_in, const int* in_sizes, int n_in,
                              void* d_out, int out_size, void* d_ws, size_t ws_size,
                              hipStream_t stream) {
  (void)in_sizes; (void)n_in; (void)out_size; (void)ws_size;
  float* ws = (float*)d_ws;

  k_pre<<<1, 256, 0, stream>>>(
      (const float*)d_in[3], (const float*)d_in[10], (const float*)d_in[11],
      (const float*)d_in[12], (const float*)d_in[6], ws);

  k_enc<<<BTOT / 256, 256, 0, stream>>>(
      (const int*)d_in[1], (const int*)d_in[2],
      (const float*)d_in[4], (const float*)d_in[5],
      (const float*)d_in[7],
      (const float*)d_in[8], (const float*)d_in[9],
      ws);

  k_attn<<<BTOT / 256, 256, 0, stream>>>(
      (const int*)d_in[0],
      (const float*)d_in[3],
      (const float*)d_in[10], (const float*)d_in[11],
      (const float*)d_in[13],
      (const float*)d_in[14], (const float*)d_in[15],
      (const float*)d_in[16], (const float*)d_in[17],
      (const float*)d_in[18], (const float*)d_in[19],
      ws, (float*)d_out);
}